// Round 1
// baseline (803.295 us; speedup 1.0000x reference)
//
#include <hip/hip_runtime.h>

typedef __attribute__((ext_vector_type(8))) short bf8;
typedef __attribute__((ext_vector_type(4))) short sh4;
typedef __attribute__((ext_vector_type(4))) float f32x4;

#define MFMA(a, b, c) __builtin_amdgcn_mfma_f32_16x16x32_bf16((a), (b), (c), 0, 0, 0)

__device__ __forceinline__ short f2bf(float f) {
    unsigned u = __builtin_bit_cast(unsigned, f);
    unsigned r = (u + 0x7fffu + ((u >> 16) & 1u)) >> 16;
    return (short)(r & 0xffffu);
}

// ---------------- prep: fold LN affines + 1/sqrt(d) into bf16 weights ----------------
// rows 0..767  : w_eff[r][ic] = w_in[r][ic] * g_sec[ic] * (sec==Q ? 1/sqrt(32) : 1)
//                b_eff[r]     = scale * (b_in[r] + sum_ic w_in[r][ic]*b_sec[ic])
// rows 768..1023: w_out_bf = bf16(w_out)
__global__ __launch_bounds__(256) void prep_kernel(
    const float* __restrict__ w_in, const float* __restrict__ b_in,
    const float* __restrict__ w_out,
    const float* __restrict__ g_q, const float* __restrict__ b_q,
    const float* __restrict__ g_k, const float* __restrict__ b_k,
    const float* __restrict__ g_v, const float* __restrict__ b_v,
    short* __restrict__ w_eff, short* __restrict__ w_out_bf,
    float* __restrict__ b_eff)
{
    const int w = threadIdx.x >> 6, l = threadIdx.x & 63;
    const int r = blockIdx.x * 4 + w;
    if (r < 768) {
        const int sec = r >> 8;
        const float* g = (sec == 0) ? g_q : ((sec == 1) ? g_k : g_v);
        const float* b = (sec == 0) ? b_q : ((sec == 1) ? b_k : b_v);
        const float scale = (sec == 0) ? 0.17677669529663689f : 1.0f;
        float4 wv = *(const float4*)(w_in + r * 256 + l * 4);
        float4 gv = *(const float4*)(g + l * 4);
        float4 bv = *(const float4*)(b + l * 4);
        sh4 o;
        o.x = f2bf(wv.x * gv.x * scale);
        o.y = f2bf(wv.y * gv.y * scale);
        o.z = f2bf(wv.z * gv.z * scale);
        o.w = f2bf(wv.w * gv.w * scale);
        *(sh4*)(w_eff + r * 256 + l * 4) = o;
        float pd = wv.x * bv.x + wv.y * bv.y + wv.z * bv.z + wv.w * bv.w;
        #pragma unroll
        for (int m = 32; m >= 1; m >>= 1) pd += __shfl_xor(pd, m);
        if (l == 0) b_eff[r] = scale * (b_in[r] + pd);
    } else {
        const int rr = r - 768;
        float4 wv = *(const float4*)(w_out + rr * 256 + l * 4);
        sh4 o;
        o.x = f2bf(wv.x); o.y = f2bf(wv.y); o.z = f2bf(wv.z); o.w = f2bf(wv.w);
        *(sh4*)(w_out_bf + rr * 256 + l * 4) = o;
    }
}

// ---------------- main: one block (512 thr = 8 waves) per 8x8 window ----------------
// LDS layout (byte offsets), liveness-overlapped:
//   xn [64][264] @0        (33792)  normalized window, bf16
//   qs [64][264] @33792    (33792)
//   ks [64][264] @67584    (33792)
//   vt [256][72] @101376   (36864)  v transposed: [oc][token]
//   ps [8][64][72] @0      (73728)  P, overlaps xn+qs+head of ks (dead after scores)
//   os [64][264] @0        (33792)  attn out, overlaps ps (dead after PV)
//   stats [64][4] @138240  (1024)   per-row {sum,sumsq} x 2 col-halves
__global__ __launch_bounds__(512, 2) void win_attn_kernel(
    const float* __restrict__ x,
    const short* __restrict__ w_eff,
    const short* __restrict__ w_out_bf,
    const float* __restrict__ b_eff,
    const float* __restrict__ b_out,
    const float* __restrict__ g_o, const float* __restrict__ b_o,
    float* __restrict__ y)
{
    __shared__ char smem[139264];
    short* xn = (short*)(smem);
    short* qs = (short*)(smem + 33792);
    short* ks = (short*)(smem + 67584);
    short* vt = (short*)(smem + 101376);
    short* ps = (short*)(smem);
    short* os = (short*)(smem);
    float* stats = (float*)(smem + 138240);

    const int tid = threadIdx.x;
    const int w = tid >> 6, l = tid & 63;
    const int wi = blockIdx.x;
    const int bimg = wi >> 6;
    const int hb = (wi >> 3) & 7, wb = wi & 7;
    const int base = ((bimg * 64 + hb * 8) * 64 + wb * 8) * 256;

    const int lm = l & 15;          // col-lane within 16
    const int lh = l >> 4;          // k-block / row-group
    const int koff = lh * 8;

    // ---- Phase 1: load + LN (shared mean/var) -> xn bf16 ----
    #pragma unroll
    for (int t8 = 0; t8 < 8; ++t8) {
        const int t = w * 8 + t8;
        const int off = base + ((t >> 3) * 64 + (t & 7)) * 256;
        float4 xv = *(const float4*)(x + off + l * 4);
        float s = xv.x + xv.y + xv.z + xv.w;
        float s2 = xv.x * xv.x + xv.y * xv.y + xv.z * xv.z + xv.w * xv.w;
        #pragma unroll
        for (int m = 32; m >= 1; m >>= 1) { s += __shfl_xor(s, m); s2 += __shfl_xor(s2, m); }
        const float mean = s * (1.f / 256.f);
        const float var = s2 * (1.f / 256.f) - mean * mean;
        const float rstd = rsqrtf(var + 1e-5f);
        sh4 xb;
        xb.x = f2bf((xv.x - mean) * rstd);
        xb.y = f2bf((xv.y - mean) * rstd);
        xb.z = f2bf((xv.z - mean) * rstd);
        xb.w = f2bf((xv.w - mean) * rstd);
        *(sh4*)(xn + t * 264 + l * 4) = xb;
    }
    __syncthreads();

    // ---- Phase 2: QKV projection [64,256]@[256,768], wave grid 4M x 2N ----
    {
        const int wm = w >> 1, wn = w & 1;
        const int arow = wm * 16 + lm;
        f32x4 acc[24];
        #pragma unroll
        for (int i = 0; i < 24; ++i) acc[i] = f32x4{0.f, 0.f, 0.f, 0.f};
        #pragma unroll
        for (int kk = 0; kk < 8; ++kk) {
            bf8 a = *(const bf8*)(xn + arow * 264 + kk * 32 + koff);
            #pragma unroll
            for (int nf = 0; nf < 24; ++nf) {
                const int col = wn * 384 + nf * 16 + lm;
                bf8 b = *(const bf8*)(w_eff + col * 256 + kk * 32 + koff);
                acc[nf] = MFMA(a, b, acc[nf]);
            }
        }
        #pragma unroll
        for (int nf = 0; nf < 24; ++nf) {
            const int col = wn * 384 + nf * 16 + lm;
            const float be = b_eff[col];
            #pragma unroll
            for (int j = 0; j < 4; ++j) {
                const int row = wm * 16 + lh * 4 + j;
                const short bv = f2bf(acc[nf][j] + be);
                if (col < 256)      qs[row * 264 + col] = bv;
                else if (col < 512) ks[row * 264 + (col - 256)] = bv;
                else                vt[(col - 512) * 72 + row] = bv;
            }
        }
    }
    __syncthreads();

    // ---- Phase 3: scores + softmax (wave = head), scale pre-folded into q ----
    f32x4 sc[4][4];
    {
        const int hh = w;
        bf8 af[4], bfr[4];
        #pragma unroll
        for (int mi = 0; mi < 4; ++mi)
            af[mi] = *(const bf8*)(qs + (mi * 16 + lm) * 264 + hh * 32 + koff);
        #pragma unroll
        for (int ni = 0; ni < 4; ++ni)
            bfr[ni] = *(const bf8*)(ks + (ni * 16 + lm) * 264 + hh * 32 + koff);
        #pragma unroll
        for (int mi = 0; mi < 4; ++mi)
            #pragma unroll
            for (int ni = 0; ni < 4; ++ni)
                sc[mi][ni] = MFMA(af[mi], bfr[ni], (f32x4{0.f, 0.f, 0.f, 0.f}));
        // softmax over keys = 4 ni frags x 16 lanes (bits 0-3)
        #pragma unroll
        for (int mi = 0; mi < 4; ++mi) {
            #pragma unroll
            for (int j = 0; j < 4; ++j) {
                float mx = fmaxf(fmaxf(sc[mi][0][j], sc[mi][1][j]),
                                 fmaxf(sc[mi][2][j], sc[mi][3][j]));
                #pragma unroll
                for (int m = 1; m < 16; m <<= 1) mx = fmaxf(mx, __shfl_xor(mx, m));
                float e0 = __expf(sc[mi][0][j] - mx);
                float e1 = __expf(sc[mi][1][j] - mx);
                float e2 = __expf(sc[mi][2][j] - mx);
                float e3 = __expf(sc[mi][3][j] - mx);
                float sum = e0 + e1 + e2 + e3;
                #pragma unroll
                for (int m = 1; m < 16; m <<= 1) sum += __shfl_xor(sum, m);
                const float rs = 1.0f / sum;
                sc[mi][0][j] = e0 * rs; sc[mi][1][j] = e1 * rs;
                sc[mi][2][j] = e2 * rs; sc[mi][3][j] = e3 * rs;
            }
        }
    }
    __syncthreads();
    // write P (overwrites xn/qs/ks-head region)
    {
        const int hh = w;
        #pragma unroll
        for (int mi = 0; mi < 4; ++mi)
            #pragma unroll
            for (int ni = 0; ni < 4; ++ni)
                #pragma unroll
                for (int j = 0; j < 4; ++j) {
                    const int row = mi * 16 + lh * 4 + j;
                    const int colk = ni * 16 + lm;
                    ps[(hh * 64 + row) * 72 + colk] = f2bf(sc[mi][ni][j]);
                }
    }
    __syncthreads();

    // ---- Phase 3.5: PV (wave = head), acc stays in regs ----
    f32x4 ov[4][2];
    {
        const int hh = w;
        #pragma unroll
        for (int am = 0; am < 4; ++am)
            #pragma unroll
            for (int nf = 0; nf < 2; ++nf) ov[am][nf] = f32x4{0.f, 0.f, 0.f, 0.f};
        #pragma unroll
        for (int kk = 0; kk < 2; ++kk) {
            bf8 pa[4], vb[2];
            #pragma unroll
            for (int am = 0; am < 4; ++am)
                pa[am] = *(const bf8*)(ps + (hh * 64 + am * 16 + lm) * 72 + kk * 32 + koff);
            #pragma unroll
            for (int nf = 0; nf < 2; ++nf)
                vb[nf] = *(const bf8*)(vt + (hh * 32 + nf * 16 + lm) * 72 + kk * 32 + koff);
            #pragma unroll
            for (int am = 0; am < 4; ++am)
                #pragma unroll
                for (int nf = 0; nf < 2; ++nf)
                    ov[am][nf] = MFMA(pa[am], vb[nf], ov[am][nf]);
        }
    }
    __syncthreads();
    // write attn out (overwrites ps region)
    {
        const int hh = w;
        #pragma unroll
        for (int am = 0; am < 4; ++am)
            #pragma unroll
            for (int nf = 0; nf < 2; ++nf)
                #pragma unroll
                for (int j = 0; j < 4; ++j) {
                    const int row = am * 16 + lh * 4 + j;
                    const int col = hh * 32 + nf * 16 + lm;
                    os[row * 264 + col] = f2bf(ov[am][nf][j]);
                }
    }
    __syncthreads();

    // ---- Phase 4: out_proj + residual + final LN + store ----
    {
        const int wm = w >> 1, wn = w & 1;
        f32x4 acc[8];
        #pragma unroll
        for (int i = 0; i < 8; ++i) acc[i] = f32x4{0.f, 0.f, 0.f, 0.f};
        #pragma unroll
        for (int kk = 0; kk < 8; ++kk) {
            bf8 a = *(const bf8*)(os + (wm * 16 + lm) * 264 + kk * 32 + koff);
            #pragma unroll
            for (int nf = 0; nf < 8; ++nf) {
                const int col = wn * 128 + nf * 16 + lm;
                bf8 b = *(const bf8*)(w_out_bf + col * 256 + kk * 32 + koff);
                acc[nf] = MFMA(a, b, acc[nf]);
            }
        }
        float vals[8][4];
        float s[4] = {0.f, 0.f, 0.f, 0.f}, s2[4] = {0.f, 0.f, 0.f, 0.f};
        #pragma unroll
        for (int nf = 0; nf < 8; ++nf) {
            const int col = wn * 128 + nf * 16 + lm;
            const float bo = b_out[col];
            #pragma unroll
            for (int j = 0; j < 4; ++j) {
                const int row = wm * 16 + lh * 4 + j;
                const int off = base + ((row >> 3) * 64 + (row & 7)) * 256 + col;
                const float v = acc[nf][j] + bo + x[off];
                vals[nf][j] = v;
                s[j] += v; s2[j] += v * v;
            }
        }
        #pragma unroll
        for (int j = 0; j < 4; ++j) {
            #pragma unroll
            for (int m = 1; m < 16; m <<= 1) {
                s[j] += __shfl_xor(s[j], m);
                s2[j] += __shfl_xor(s2[j], m);
            }
        }
        if (lm == 0) {
            #pragma unroll
            for (int j = 0; j < 4; ++j) {
                const int row = wm * 16 + lh * 4 + j;
                stats[row * 4 + wn * 2 + 0] = s[j];
                stats[row * 4 + wn * 2 + 1] = s2[j];
            }
        }
        __syncthreads();
        #pragma unroll
        for (int nf = 0; nf < 8; ++nf) {
            const int col = wn * 128 + nf * 16 + lm;
            const float go = g_o[col], bo2 = b_o[col];
            #pragma unroll
            for (int j = 0; j < 4; ++j) {
                const int row = wm * 16 + lh * 4 + j;
                const float S = stats[row * 4 + 0] + stats[row * 4 + 2];
                const float S2 = stats[row * 4 + 1] + stats[row * 4 + 3];
                const float mean = S * (1.f / 256.f);
                const float var = S2 * (1.f / 256.f) - mean * mean;
                const float rstd = rsqrtf(var + 1e-5f);
                const int off = base + ((row >> 3) * 64 + (row & 7)) * 256 + col;
                y[off] = (vals[nf][j] - mean) * rstd * go + bo2;
            }
        }
    }
}

extern "C" void kernel_launch(void* const* d_in, const int* in_sizes, int n_in,
                              void* d_out, int out_size, void* d_ws, size_t ws_size,
                              hipStream_t stream) {
    (void)in_sizes; (void)n_in; (void)out_size; (void)ws_size;
    const float* x     = (const float*)d_in[0];
    const float* w_in  = (const float*)d_in[1];
    const float* b_in  = (const float*)d_in[2];
    const float* w_out = (const float*)d_in[3];
    const float* b_out = (const float*)d_in[4];
    const float* g_q   = (const float*)d_in[5];
    const float* b_q   = (const float*)d_in[6];
    const float* g_k   = (const float*)d_in[7];
    const float* b_k   = (const float*)d_in[8];
    const float* g_v   = (const float*)d_in[9];
    const float* b_v   = (const float*)d_in[10];
    const float* g_o   = (const float*)d_in[11];
    const float* b_o   = (const float*)d_in[12];
    float* y = (float*)d_out;

    short* w_eff    = (short*)d_ws;            // [768][256] bf16
    short* w_out_bf = w_eff + 768 * 256;       // [256][256] bf16
    float* b_eff    = (float*)(w_out_bf + 256 * 256);  // [768] f32

    prep_kernel<<<256, 256, 0, stream>>>(w_in, b_in, w_out, g_q, b_q, g_k, b_k,
                                         g_v, b_v, w_eff, w_out_bf, b_eff);
    win_attn_kernel<<<2048, 512, 0, stream>>>(x, w_eff, w_out_bf, b_eff, b_out,
                                              g_o, b_o, y);
}

// Round 2
// 446.338 us; speedup vs baseline: 1.7997x; 1.7997x over previous
//
#include <hip/hip_runtime.h>

typedef __attribute__((ext_vector_type(8))) short bf8;
typedef __attribute__((ext_vector_type(4))) short sh4;
typedef __attribute__((ext_vector_type(4))) float f32x4;

#define MFMA(a, b, c) __builtin_amdgcn_mfma_f32_16x16x32_bf16((a), (b), (c), 0, 0, 0)

__device__ __forceinline__ short f2bf(float f) {
    unsigned u = __builtin_bit_cast(unsigned, f);
    unsigned r = (u + 0x7fffu + ((u >> 16) & 1u)) >> 16;
    return (short)(r & 0xffffu);
}

// ---------------- prep ----------------
// wfrag layout (shorts): QKV frags f=0..383 (f = colblk*8+kk) at f*512 + l*8+j
//   lane l=(lh*16+lm) short j holds w_eff[col=colblk*16+lm][ch=kk*32+lh*8+j]
// OP frags f=0..127 at 196608 + f*512 (+ same lane mapping, w_out)
// b_eff[768] float after wfrag.
__global__ __launch_bounds__(256) void prep_kernel(
    const float* __restrict__ w_in, const float* __restrict__ b_in,
    const float* __restrict__ w_out,
    const float* __restrict__ g_q, const float* __restrict__ b_q,
    const float* __restrict__ g_k, const float* __restrict__ b_k,
    const float* __restrict__ g_v, const float* __restrict__ b_v,
    short* __restrict__ wfrag, float* __restrict__ b_eff)
{
    const int w = threadIdx.x >> 6, l = threadIdx.x & 63;
    const int lm = l & 15, lh = l >> 4;
    const int bid = blockIdx.x;
    if (bid < 192) {
        // bias fold for row r
        const int r = bid * 4 + w;
        const int sec = r >> 8;
        const float* bb = (sec == 0) ? b_q : ((sec == 1) ? b_k : b_v);
        const float scale = (sec == 0) ? 0.17677669529663689f : 1.0f;
        float4 wv = *(const float4*)(w_in + r * 256 + l * 4);
        float4 bv = *(const float4*)(bb + l * 4);
        float pd = wv.x * bv.x + wv.y * bv.y + wv.z * bv.z + wv.w * bv.w;
        #pragma unroll
        for (int m = 32; m >= 1; m >>= 1) pd += __shfl_xor(pd, m);
        if (l == 0) b_eff[r] = scale * (b_in[r] + pd);
    } else if (bid < 288) {
        const int f = (bid - 192) * 4 + w;   // 0..383
        const int c = f >> 3, kk = f & 7;
        const int col = c * 16 + lm;
        const int sec = col >> 8;
        const float* g = (sec == 0) ? g_q : ((sec == 1) ? g_k : g_v);
        const float scale = (sec == 0) ? 0.17677669529663689f : 1.0f;
        const int ch = kk * 32 + lh * 8;
        float4 w0 = *(const float4*)(w_in + col * 256 + ch);
        float4 w1 = *(const float4*)(w_in + col * 256 + ch + 4);
        float4 g0 = *(const float4*)(g + ch);
        float4 g1 = *(const float4*)(g + ch + 4);
        bf8 o;
        o[0] = f2bf(w0.x * g0.x * scale); o[1] = f2bf(w0.y * g0.y * scale);
        o[2] = f2bf(w0.z * g0.z * scale); o[3] = f2bf(w0.w * g0.w * scale);
        o[4] = f2bf(w1.x * g1.x * scale); o[5] = f2bf(w1.y * g1.y * scale);
        o[6] = f2bf(w1.z * g1.z * scale); o[7] = f2bf(w1.w * g1.w * scale);
        *(bf8*)(wfrag + f * 512 + l * 8) = o;
    } else {
        const int f = (bid - 288) * 4 + w;   // 0..127
        const int c = f >> 3, kk = f & 7;
        const int col = c * 16 + lm;
        const int ch = kk * 32 + lh * 8;
        float4 w0 = *(const float4*)(w_out + col * 256 + ch);
        float4 w1 = *(const float4*)(w_out + col * 256 + ch + 4);
        bf8 o;
        o[0] = f2bf(w0.x); o[1] = f2bf(w0.y); o[2] = f2bf(w0.z); o[3] = f2bf(w0.w);
        o[4] = f2bf(w1.x); o[5] = f2bf(w1.y); o[6] = f2bf(w1.z); o[7] = f2bf(w1.w);
        *(bf8*)(wfrag + 196608 + f * 512 + l * 8) = o;
    }
}

// ---------------- main: one block (1024 thr = 16 waves) per 8x8 window ----------------
// LDS (byte offsets), liveness-overlapped:
//   qs [64][264] @0       (33792)   ks [64][264] @33792 (33792)
//   ps [8][64][72] @0     (73728)   overlaps qs+ks (dead after scores read)
//   vt frag-linear @73728 (32768)   32 frags (hh*4+nf*2+kk) x 1KB
//   os [64][264] @0       (33792)   overlaps ps
//   xn [64][264] @106496  (33792)
//   stats [64][2] f32 @140288 (512)
__global__ __launch_bounds__(1024) void win_attn_kernel(
    const float* __restrict__ x, const short* __restrict__ wfrag,
    const float* __restrict__ b_eff, const float* __restrict__ b_out,
    const float* __restrict__ g_o, const float* __restrict__ b_o,
    float* __restrict__ y)
{
    __shared__ char smem[140800];
    short* qs = (short*)(smem);
    short* ks = (short*)(smem + 33792);
    short* ps = (short*)(smem);
    short* vt = (short*)(smem + 73728);
    short* os = (short*)(smem);
    short* xn = (short*)(smem + 106496);
    float* stats = (float*)(smem + 140288);

    const int tid = threadIdx.x;
    const int w = tid >> 6, l = tid & 63;
    const int lm = l & 15, lh = l >> 4, koff = lh * 8;
    const int wi = blockIdx.x;
    const int bimg = wi >> 6, hb = (wi >> 3) & 7, wb = wi & 7;
    const int base = ((bimg * 64 + hb * 8) * 64 + wb * 8) * 256;

    if (tid < 128) stats[tid] = 0.f;

    // ---- Phase 1: load + LN -> xn (16 waves x 4 tokens) ----
    #pragma unroll
    for (int i = 0; i < 4; ++i) {
        const int t = w * 4 + i;
        const int off = base + ((t >> 3) * 64 + (t & 7)) * 256;
        float4 xv = *(const float4*)(x + off + l * 4);
        float s = xv.x + xv.y + xv.z + xv.w;
        float s2 = xv.x * xv.x + xv.y * xv.y + xv.z * xv.z + xv.w * xv.w;
        #pragma unroll
        for (int m = 32; m >= 1; m >>= 1) { s += __shfl_xor(s, m); s2 += __shfl_xor(s2, m); }
        const float mean = s * (1.f / 256.f);
        const float rstd = rsqrtf(s2 * (1.f / 256.f) - mean * mean + 1e-5f);
        sh4 xb;
        xb[0] = f2bf((xv.x - mean) * rstd); xb[1] = f2bf((xv.y - mean) * rstd);
        xb[2] = f2bf((xv.z - mean) * rstd); xb[3] = f2bf((xv.w - mean) * rstd);
        *(sh4*)(xn + t * 264 + l * 4) = xb;
    }
    __syncthreads();

    // ---- Phase 2: QKV. wave (wm=w>>3: 2x16 rows, wn=w&7: 6 colblks) ----
    {
        const int wm = w >> 3, wn = w & 7;
        f32x4 acc[2][6];
        #pragma unroll
        for (int mi = 0; mi < 2; ++mi)
            #pragma unroll
            for (int nf = 0; nf < 6; ++nf) acc[mi][nf] = f32x4{0.f, 0.f, 0.f, 0.f};
        #pragma unroll
        for (int kk = 0; kk < 8; ++kk) {
            bf8 a0 = *(const bf8*)(xn + (wm * 32 + lm) * 264 + kk * 32 + koff);
            bf8 a1 = *(const bf8*)(xn + (wm * 32 + 16 + lm) * 264 + kk * 32 + koff);
            #pragma unroll
            for (int nf = 0; nf < 6; ++nf) {
                bf8 b = *(const bf8*)(wfrag + ((wn * 6 + nf) * 8 + kk) * 512 + l * 8);
                acc[0][nf] = MFMA(a0, b, acc[0][nf]);
                acc[1][nf] = MFMA(a1, b, acc[1][nf]);
            }
        }
        #pragma unroll
        for (int nf = 0; nf < 6; ++nf) {
            const int col = (wn * 6 + nf) * 16 + lm;
            const float be = b_eff[col];
            #pragma unroll
            for (int mi = 0; mi < 2; ++mi)
                #pragma unroll
                for (int j = 0; j < 4; ++j) {
                    const int row = wm * 32 + mi * 16 + lh * 4 + j;
                    const short bv = f2bf(acc[mi][nf][j] + be);
                    if (col < 256) qs[row * 264 + col] = bv;
                    else if (col < 512) ks[row * 264 + (col - 256)] = bv;
                    else {
                        const int d = col - 512, key = row;
                        vt[((d >> 5) * 4 + ((d >> 4) & 1) * 2 + (key >> 5)) * 512
                           + ((key >> 3) & 3) * 128 + (d & 15) * 8 + (key & 7)] = bv;
                    }
                }
        }
    }
    __syncthreads();

    // ---- Phase 3: scores + softmax. wave (hh=w&7, qh=w>>3: 2x16 query rows) ----
    const int hh = w & 7, qh = w >> 3;
    f32x4 sc[2][4];
    {
        bf8 af[2], bk[4];
        #pragma unroll
        for (int mi = 0; mi < 2; ++mi)
            af[mi] = *(const bf8*)(qs + (qh * 32 + mi * 16 + lm) * 264 + hh * 32 + koff);
        #pragma unroll
        for (int ni = 0; ni < 4; ++ni)
            bk[ni] = *(const bf8*)(ks + (ni * 16 + lm) * 264 + hh * 32 + koff);
        #pragma unroll
        for (int mi = 0; mi < 2; ++mi)
            #pragma unroll
            for (int ni = 0; ni < 4; ++ni)
                sc[mi][ni] = MFMA(af[mi], bk[ni], (f32x4{0.f, 0.f, 0.f, 0.f}));
        #pragma unroll
        for (int mi = 0; mi < 2; ++mi)
            #pragma unroll
            for (int j = 0; j < 4; ++j) {
                float mx = fmaxf(fmaxf(sc[mi][0][j], sc[mi][1][j]),
                                 fmaxf(sc[mi][2][j], sc[mi][3][j]));
                #pragma unroll
                for (int m = 1; m < 16; m <<= 1) mx = fmaxf(mx, __shfl_xor(mx, m));
                float e0 = __expf(sc[mi][0][j] - mx), e1 = __expf(sc[mi][1][j] - mx);
                float e2 = __expf(sc[mi][2][j] - mx), e3 = __expf(sc[mi][3][j] - mx);
                float sum = e0 + e1 + e2 + e3;
                #pragma unroll
                for (int m = 1; m < 16; m <<= 1) sum += __shfl_xor(sum, m);
                const float rs = 1.0f / sum;
                sc[mi][0][j] = e0 * rs; sc[mi][1][j] = e1 * rs;
                sc[mi][2][j] = e2 * rs; sc[mi][3][j] = e3 * rs;
            }
    }
    __syncthreads();   // all qs/ks reads done
    #pragma unroll
    for (int mi = 0; mi < 2; ++mi)
        #pragma unroll
        for (int ni = 0; ni < 4; ++ni)
            #pragma unroll
            for (int j = 0; j < 4; ++j)
                ps[(hh * 64 + qh * 32 + mi * 16 + lh * 4 + j) * 72 + ni * 16 + lm] =
                    f2bf(sc[mi][ni][j]);
    __syncthreads();

    // ---- Phase 3.5: PV. wave (hh, qh) ----
    f32x4 ov[2][2];
    {
        #pragma unroll
        for (int am = 0; am < 2; ++am)
            #pragma unroll
            for (int nf = 0; nf < 2; ++nf) ov[am][nf] = f32x4{0.f, 0.f, 0.f, 0.f};
        #pragma unroll
        for (int kk = 0; kk < 2; ++kk) {
            bf8 pa[2], vb[2];
            #pragma unroll
            for (int am = 0; am < 2; ++am)
                pa[am] = *(const bf8*)(ps + (hh * 64 + qh * 32 + am * 16 + lm) * 72 + kk * 32 + koff);
            #pragma unroll
            for (int nf = 0; nf < 2; ++nf)
                vb[nf] = *(const bf8*)(vt + (hh * 4 + nf * 2 + kk) * 512 + l * 8);
            #pragma unroll
            for (int am = 0; am < 2; ++am)
                #pragma unroll
                for (int nf = 0; nf < 2; ++nf)
                    ov[am][nf] = MFMA(pa[am], vb[nf], ov[am][nf]);
        }
    }
    __syncthreads();   // all ps reads done
    #pragma unroll
    for (int am = 0; am < 2; ++am)
        #pragma unroll
        for (int nf = 0; nf < 2; ++nf)
            #pragma unroll
            for (int j = 0; j < 4; ++j)
                os[(qh * 32 + am * 16 + lh * 4 + j) * 264 + hh * 32 + nf * 16 + lm] =
                    f2bf(ov[am][nf][j]);
    __syncthreads();

    // ---- Phase 4: out_proj + residual + final LN. wave (wm=w>>3, wn=w&7: 2 colblks) ----
    {
        const int wm = w >> 3, wn = w & 7;
        f32x4 acc[2][2];
        #pragma unroll
        for (int mi = 0; mi < 2; ++mi)
            #pragma unroll
            for (int nf = 0; nf < 2; ++nf) acc[mi][nf] = f32x4{0.f, 0.f, 0.f, 0.f};
        #pragma unroll
        for (int kk = 0; kk < 8; ++kk) {
            bf8 a0 = *(const bf8*)(os + (wm * 32 + lm) * 264 + kk * 32 + koff);
            bf8 a1 = *(const bf8*)(os + (wm * 32 + 16 + lm) * 264 + kk * 32 + koff);
            #pragma unroll
            for (int nf = 0; nf < 2; ++nf) {
                bf8 b = *(const bf8*)(wfrag + 196608 + ((wn * 2 + nf) * 8 + kk) * 512 + l * 8);
                acc[0][nf] = MFMA(a0, b, acc[0][nf]);
                acc[1][nf] = MFMA(a1, b, acc[1][nf]);
            }
        }
        float vals[2][2][4];
        float s[2][4], s2[2][4];
        #pragma unroll
        for (int mi = 0; mi < 2; ++mi)
            #pragma unroll
            for (int j = 0; j < 4; ++j) { s[mi][j] = 0.f; s2[mi][j] = 0.f; }
        #pragma unroll
        for (int nf = 0; nf < 2; ++nf) {
            const int col = wn * 32 + nf * 16 + lm;
            const float bo = b_out[col];
            #pragma unroll
            for (int mi = 0; mi < 2; ++mi)
                #pragma unroll
                for (int j = 0; j < 4; ++j) {
                    const int row = wm * 32 + mi * 16 + lh * 4 + j;
                    const int off = base + ((row >> 3) * 64 + (row & 7)) * 256 + col;
                    const float v = acc[mi][nf][j] + bo + x[off];
                    vals[mi][nf][j] = v;
                    s[mi][j] += v; s2[mi][j] += v * v;
                }
        }
        #pragma unroll
        for (int mi = 0; mi < 2; ++mi)
            #pragma unroll
            for (int j = 0; j < 4; ++j) {
                #pragma unroll
                for (int m = 1; m < 16; m <<= 1) {
                    s[mi][j] += __shfl_xor(s[mi][j], m);
                    s2[mi][j] += __shfl_xor(s2[mi][j], m);
                }
            }
        if (lm == 0) {
            #pragma unroll
            for (int mi = 0; mi < 2; ++mi)
                #pragma unroll
                for (int j = 0; j < 4; ++j) {
                    const int row = wm * 32 + mi * 16 + lh * 4 + j;
                    atomicAdd(&stats[row * 2 + 0], s[mi][j]);
                    atomicAdd(&stats[row * 2 + 1], s2[mi][j]);
                }
        }
        __syncthreads();
        #pragma unroll
        for (int mi = 0; mi < 2; ++mi)
            #pragma unroll
            for (int j = 0; j < 4; ++j) {
                const int row = wm * 32 + mi * 16 + lh * 4 + j;
                const float S = stats[row * 2 + 0], S2 = stats[row * 2 + 1];
                const float mean = S * (1.f / 256.f);
                const float rstd = rsqrtf(S2 * (1.f / 256.f) - mean * mean + 1e-5f);
                #pragma unroll
                for (int nf = 0; nf < 2; ++nf) {
                    const int col = wn * 32 + nf * 16 + lm;
                    const int off = base + ((row >> 3) * 64 + (row & 7)) * 256 + col;
                    y[off] = (vals[mi][nf][j] - mean) * rstd * g_o[col] + b_o[col];
                }
            }
    }
}

extern "C" void kernel_launch(void* const* d_in, const int* in_sizes, int n_in,
                              void* d_out, int out_size, void* d_ws, size_t ws_size,
                              hipStream_t stream) {
    (void)in_sizes; (void)n_in; (void)out_size; (void)ws_size;
    const float* x     = (const float*)d_in[0];
    const float* w_in  = (const float*)d_in[1];
    const float* b_in  = (const float*)d_in[2];
    const float* w_out = (const float*)d_in[3];
    const float* b_out = (const float*)d_in[4];
    const float* g_q   = (const float*)d_in[5];
    const float* b_q   = (const float*)d_in[6];
    const float* g_k   = (const float*)d_in[7];
    const float* b_k   = (const float*)d_in[8];
    const float* g_v   = (const float*)d_in[9];
    const float* b_v   = (const float*)d_in[10];
    const float* g_o   = (const float*)d_in[11];
    const float* b_o   = (const float*)d_in[12];
    float* y = (float*)d_out;

    short* wfrag = (short*)d_ws;                 // 512 frags x 512 shorts = 512 KB
    float* b_eff = (float*)(wfrag + 512 * 512);  // [768] f32

    prep_kernel<<<320, 256, 0, stream>>>(w_in, b_in, w_out, g_q, b_q, g_k, b_k,
                                         g_v, b_v, wfrag, b_eff);
    win_attn_kernel<<<2048, 1024, 0, stream>>>(x, wfrag, b_eff, b_out, g_o, b_o, y);
}